// Round 1
// baseline (782.869 us; speedup 1.0000x reference)
//
#include <hip/hip_runtime.h>
#include <math.h>

#define B 512
#define T 256
#define N 200
#define H 64
#define NN (N*N)     // 40000
#define TN (T*N)     // 51200
#define NH (N*H)     // 12800

// ---------------- K0: per-(sample,node) mean and 1/std ----------------
__global__ __launch_bounds__(256) void k_stats(const float* __restrict__ data,
                                               float* __restrict__ mean,
                                               float* __restrict__ rd) {
    int b = blockIdx.x;
    int n = threadIdx.x;
    if (n >= N) return;
    const float* p = data + (size_t)b * TN + n;
    float s = 0.f, ss = 0.f;
#pragma unroll 4
    for (int t = 0; t < T; ++t) {
        float v = p[(size_t)t * N];
        s += v; ss += v * v;
    }
    float mu = s * (1.f / T);
    float var = ss - s * mu;              // sum((x-mu)^2) = sum(x^2) - T*mu^2
    mean[b * N + n] = mu;
    rd[b * N + n] = (var > 0.f) ? rsqrtf(var) : 0.f;
}

// ---------------- K1: A = |corr|, 64x64 tiles, upper triangle + mirror ----------------
__global__ __launch_bounds__(256) void k_corr(const float* __restrict__ data,
                                              const float* __restrict__ mean,
                                              const float* __restrict__ rd,
                                              float* __restrict__ A) {
    // grid = 512 samples * 10 upper-tri tiles = 5120 blocks.
    // XCD-grouping: blocks with blk%8==x handle samples [x*64, x*64+64).
    int blk = blockIdx.x;
    int x = blk & 7;
    int q = blk >> 3;                 // 0..639
    int b = x * 64 + q / 10;
    int t = q - (q / 10) * 10;        // 0..9
    int ti, tj;
    if      (t < 4) { ti = 0; tj = t;     }
    else if (t < 7) { ti = 1; tj = t - 3; }
    else if (t < 9) { ti = 2; tj = t - 5; }
    else            { ti = 3; tj = 3;     }
    int i0 = ti * 64, j0 = tj * 64;

    __shared__ float Xi[32][64];
    __shared__ float Xj[32][64];
    __shared__ float Tr[64][65];      // padded transpose/staging buffer

    int tid = threadIdx.x;
    int tx = tid & 15, ty = tid >> 4;
    int tx4 = tx * 4, ty4 = ty * 4;

    float acc[4][4] = {};
    const float* db = data + (size_t)b * TN;

    for (int t0 = 0; t0 < T; t0 += 32) {
        for (int idx = tid; idx < 32 * 64; idx += 256) {
            int k = idx >> 6, n = idx & 63;
            int gi = i0 + n, gj = j0 + n;
            const float* row = db + (size_t)(t0 + k) * N;
            Xi[k][n] = (gi < N) ? row[gi] : 0.f;
            Xj[k][n] = (gj < N) ? row[gj] : 0.f;
        }
        __syncthreads();
#pragma unroll 8
        for (int k = 0; k < 32; ++k) {
            float a0 = Xi[k][ty4 + 0], a1 = Xi[k][ty4 + 1];
            float a2 = Xi[k][ty4 + 2], a3 = Xi[k][ty4 + 3];
            float c0 = Xj[k][tx4 + 0], c1 = Xj[k][tx4 + 1];
            float c2 = Xj[k][tx4 + 2], c3 = Xj[k][tx4 + 3];
            acc[0][0] += a0 * c0; acc[0][1] += a0 * c1; acc[0][2] += a0 * c2; acc[0][3] += a0 * c3;
            acc[1][0] += a1 * c0; acc[1][1] += a1 * c1; acc[1][2] += a1 * c2; acc[1][3] += a1 * c3;
            acc[2][0] += a2 * c0; acc[2][1] += a2 * c1; acc[2][2] += a2 * c2; acc[2][3] += a2 * c3;
            acc[3][0] += a3 * c0; acc[3][1] += a3 * c1; acc[3][2] += a3 * c2; acc[3][3] += a3 * c3;
        }
        __syncthreads();
    }

    // normalize to |corr|
    float mi[4], ri[4], mj[4], rj[4];
#pragma unroll
    for (int r = 0; r < 4; ++r) {
        int ii = i0 + ty4 + r;
        mi[r] = (ii < N) ? mean[b * N + ii] : 0.f;
        ri[r] = (ii < N) ? rd[b * N + ii] : 0.f;
    }
#pragma unroll
    for (int c = 0; c < 4; ++c) {
        int jj = j0 + tx4 + c;
        mj[c] = (jj < N) ? mean[b * N + jj] : 0.f;
        rj[c] = (jj < N) ? rd[b * N + jj] : 0.f;
    }
    float val[4][4];
#pragma unroll
    for (int r = 0; r < 4; ++r)
#pragma unroll
        for (int c = 0; c < 4; ++c)
            val[r][c] = fabsf((acc[r][c] - 256.f * mi[r] * mj[c]) * (ri[r] * rj[c]));

    float* Ab = A + (size_t)b * NN;

    // pass 1: direct tile (coalesced via LDS staging)
#pragma unroll
    for (int r = 0; r < 4; ++r)
#pragma unroll
        for (int c = 0; c < 4; ++c)
            Tr[ty4 + r][tx4 + c] = val[r][c];
    __syncthreads();
    for (int idx = tid; idx < 64 * 64; idx += 256) {
        int il = idx >> 6, jl = idx & 63;
        int ii = i0 + il, jj = j0 + jl;
        if (ii < N && jj < N) Ab[ii * N + jj] = Tr[il][jl];
    }

    // pass 2: mirrored tile (A is symmetric)
    if (i0 != j0) {
        __syncthreads();
#pragma unroll
        for (int r = 0; r < 4; ++r)
#pragma unroll
            for (int c = 0; c < 4; ++c)
                Tr[tx4 + c][ty4 + r] = val[r][c];
        __syncthreads();
        for (int idx = tid; idx < 64 * 64; idx += 256) {
            int jl = idx >> 6, il = idx & 63;
            int jj = j0 + jl, ii = i0 + il;
            if (ii < N && jj < N) Ab[jj * N + ii] = Tr[jl][il];
        }
    }
}

// ---------------- K2: dinv = rsqrt(rowsum(A) + 1), via colsum (A symmetric) ----------------
__global__ __launch_bounds__(256) void k_dinv(const float* __restrict__ A,
                                              float* __restrict__ dinv) {
    int b = blockIdx.x;
    int j = threadIdx.x;
    if (j >= N) return;
    const float* Ab = A + (size_t)b * NN + j;
    float s = 1.f;                        // the +I
#pragma unroll 4
    for (int i = 0; i < N; ++i) s += Ab[(size_t)i * N];
    dinv[b * N + j] = rsqrtf(s);
}

// ---------------- K3: t1 = A @ W1  (per sample, lane = hidden channel) ----------------
__global__ __launch_bounds__(256) void k_t1(const float* __restrict__ A,
                                            const float* __restrict__ W1,
                                            float* __restrict__ t1) {
    __shared__ float Ws[NH];              // 51.2 KB
    int b = blockIdx.x, tid = threadIdx.x;
    for (int idx = tid; idx < NH; idx += 256) Ws[idx] = W1[idx];
    __syncthreads();
    int w = tid >> 6, lane = tid & 63;
    const float* Ab = A + (size_t)b * NN;
    float* tb = t1 + (size_t)b * NH;
    for (int i = w; i < N; i += 4) {
        const float* Ar = Ab + i * N;
        float acc = 0.f;
        for (int j = 0; j < N; j += 4) {
            float4 av = *(const float4*)(Ar + j);
            acc += av.x * Ws[(j + 0) * H + lane];
            acc += av.y * Ws[(j + 1) * H + lane];
            acc += av.z * Ws[(j + 2) * H + lane];
            acc += av.w * Ws[(j + 3) * H + lane];
        }
        tb[i * H + lane] = acc;
    }
}

// ---------------- K4: h1 = relu(dinv_i*(A@(dinv⊙t1) + (dinv⊙t1)_i) + b1) -> d_out ----------------
__global__ __launch_bounds__(256) void k_h1(const float* __restrict__ A,
                                            const float* __restrict__ t1,
                                            const float* __restrict__ dinv,
                                            const float* __restrict__ b1,
                                            float* __restrict__ h1) {
    __shared__ float Y[NH];
    int b = blockIdx.x, tid = threadIdx.x;
    const float* dv = dinv + b * N;
    const float* tb = t1 + (size_t)b * NH;
    for (int idx = tid; idx < NH; idx += 256) {
        int j = idx >> 6;
        Y[idx] = dv[j] * tb[idx];
    }
    __syncthreads();
    int w = tid >> 6, lane = tid & 63;
    float bias = b1[lane];
    const float* Ab = A + (size_t)b * NN;
    float* hb = h1 + (size_t)b * NH;
    for (int i = w; i < N; i += 4) {
        const float* Ar = Ab + i * N;
        float acc = 0.f;
        for (int j = 0; j < N; j += 4) {
            float4 av = *(const float4*)(Ar + j);
            acc += av.x * Y[(j + 0) * H + lane];
            acc += av.y * Y[(j + 1) * H + lane];
            acc += av.z * Y[(j + 2) * H + lane];
            acc += av.w * Y[(j + 3) * H + lane];
        }
        float v = dv[i] * (acc + Y[i * H + lane]) + bias;
        hb[i * H + lane] = fmaxf(v, 0.f);
    }
}

// ---------------- K5: y2 = dinv⊙(h1@W2); out = relu(dinv_i*(A@y2 + y2_i) + b2) ----------------
__global__ __launch_bounds__(256) void k_out(const float* __restrict__ A,
                                             const float* __restrict__ dinv,
                                             const float* __restrict__ W2,
                                             const float* __restrict__ b2,
                                             float* __restrict__ out /* in: h1, out: final */) {
    __shared__ float Y2[NH];
    __shared__ float W2s[H * H];
    int b = blockIdx.x, tid = threadIdx.x;
    for (int idx = tid; idx < H * H; idx += 256) W2s[idx] = W2[idx];
    __syncthreads();
    const float* dv = dinv + b * N;
    int w = tid >> 6, lane = tid & 63;
    float* ob = out + (size_t)b * NH;
    // phase 1: y2 = dinv ⊙ (h1 @ W2) into LDS
    for (int j = w; j < N; j += 4) {
        const float* hr = ob + j * H;
        float acc = 0.f;
        for (int k = 0; k < H; k += 4) {
            float4 hv = *(const float4*)(hr + k);
            acc += hv.x * W2s[(k + 0) * H + lane];
            acc += hv.y * W2s[(k + 1) * H + lane];
            acc += hv.z * W2s[(k + 2) * H + lane];
            acc += hv.w * W2s[(k + 3) * H + lane];
        }
        Y2[j * H + lane] = dv[j] * acc;
    }
    __syncthreads();
    float bias = b2[lane];
    const float* Ab = A + (size_t)b * NN;
    for (int i = w; i < N; i += 4) {
        const float* Ar = Ab + i * N;
        float acc = 0.f;
        for (int j = 0; j < N; j += 4) {
            float4 av = *(const float4*)(Ar + j);
            acc += av.x * Y2[(j + 0) * H + lane];
            acc += av.y * Y2[(j + 1) * H + lane];
            acc += av.z * Y2[(j + 2) * H + lane];
            acc += av.w * Y2[(j + 3) * H + lane];
        }
        float v = dv[i] * (acc + Y2[i * H + lane]) + bias;
        ob[i * H + lane] = fmaxf(v, 0.f);
    }
}

extern "C" void kernel_launch(void* const* d_in, const int* in_sizes, int n_in,
                              void* d_out, int out_size, void* d_ws, size_t ws_size,
                              hipStream_t stream) {
    const float* data = (const float*)d_in[0];
    const float* W1   = (const float*)d_in[1];
    const float* b1   = (const float*)d_in[2];
    const float* W2   = (const float*)d_in[3];
    const float* b2   = (const float*)d_in[4];
    float* out = (float*)d_out;

    float* ws   = (float*)d_ws;
    float* A    = ws;                         // 20,480,000 floats
    float* mean = A + (size_t)B * NN;         // 102,400
    float* rdv  = mean + B * N;               // 102,400
    float* dinv = rdv + B * N;                // 102,400
    float* t1   = dinv + B * N;               // 6,553,600
    // total: 27,340,800 floats ≈ 109.4 MB

    hipLaunchKernelGGL(k_stats, dim3(B),      dim3(256), 0, stream, data, mean, rdv);
    hipLaunchKernelGGL(k_corr,  dim3(B * 10), dim3(256), 0, stream, data, mean, rdv, A);
    hipLaunchKernelGGL(k_dinv,  dim3(B),      dim3(256), 0, stream, A, dinv);
    hipLaunchKernelGGL(k_t1,    dim3(B),      dim3(256), 0, stream, A, W1, t1);
    hipLaunchKernelGGL(k_h1,    dim3(B),      dim3(256), 0, stream, A, t1, dinv, b1, out);
    hipLaunchKernelGGL(k_out,   dim3(B),      dim3(256), 0, stream, A, dinv, W2, b2, out);
}

// Round 2
// 432.445 us; speedup vs baseline: 1.8103x; 1.8103x over previous
//
#include <hip/hip_runtime.h>
#include <math.h>

#define B 512
#define T 256
#define N 200
#define H 64
#define NN (N*N)     // 40000
#define TN (T*N)     // 51200

typedef short short8 __attribute__((ext_vector_type(8)));
typedef float f32x4 __attribute__((ext_vector_type(4)));

__device__ __forceinline__ unsigned bf16r(float x) {
    unsigned u = __float_as_uint(x);
    return (u + 0x7fffu + ((u >> 16) & 1u)) >> 16;   // round-to-nearest-even
}

// ---------------- K0: per-(sample,node) mean and 1/std ----------------
__global__ __launch_bounds__(256) void k_stats(const float* __restrict__ data,
                                               float* __restrict__ mean,
                                               float* __restrict__ rd) {
    int b = blockIdx.x;
    int n = threadIdx.x;
    if (n >= N) return;
    const float* p = data + (size_t)b * TN + n;
    float s = 0.f, ss = 0.f;
#pragma unroll 8
    for (int t = 0; t < T; ++t) {
        float v = p[(size_t)t * N];
        s += v; ss += v * v;
    }
    float mu = s * (1.f / T);
    float var = ss - s * mu;
    mean[b * N + n] = mu;
    rd[b * N + n] = (var > 0.f) ? rsqrtf(var) : 0.f;
}

// ---------------- K1: A = |corr| via bf16 MFMA + degree atomics ----------------
__global__ __launch_bounds__(256) void k_corr(const float* __restrict__ data,
                                              const float* __restrict__ mean,
                                              const float* __restrict__ rd,
                                              float* __restrict__ A,
                                              float* __restrict__ deg) {
    int blk = blockIdx.x;
    int x = blk & 7;                  // XCD grouping: sample groups pinned per XCD slot
    int q = blk >> 3;
    int b = x * 64 + q / 10;
    int t = q - (q / 10) * 10;
    int ti, tj;
    if      (t < 4) { ti = 0; tj = t;     }
    else if (t < 7) { ti = 1; tj = t - 3; }
    else if (t < 9) { ti = 2; tj = t - 5; }
    else            { ti = 3; tj = 3;     }
    int i0 = ti * 64, j0 = tj * 64;

    __shared__ __align__(16) float Sraw[2][4096];            // 32 KB raw fp32 [t][n], aliased as Tr later
    __shared__ __align__(16) unsigned short Xt[2][4096];     // 16 KB bf16 [col][k], XOR-swizzled

    int tid = threadIdx.x;
    int lane = tid & 63, w = tid >> 6;
    const float* db = data + (size_t)b * TN;

    f32x4 acc[4] = {};

    for (int c = 0; c < 4; ++c) {                 // 4 chunks of 64 timesteps
        int t0 = c * 64;
        // stage raw fp32 [64 t][64 n] per side (coalesced float4)
        for (int side = 0; side < 2; ++side) {
            int base = side ? j0 : i0;
#pragma unroll
            for (int it = 0; it < 4; ++it) {
                int f = it * 1024 + tid * 4;
                int r = f >> 6, cc = f & 63;
                int gc = base + cc; if (gc > N - 4) gc = N - 4;   // clamp (dup cols, zeroed later)
                float4 v = *(const float4*)(db + (size_t)(t0 + r) * N + gc);
                *(float4*)(&Sraw[side][f]) = v;
            }
        }
        __syncthreads();
        // convert + transpose: Xt[side][col][k] = bf16((x - mu)*rdev), swizzled
        {
            int n = tid & 63;
            int seg = tid >> 6;
            for (int side = 0; side < 2; ++side) {
                int gcn = (side ? j0 : i0) + n;
                float mu = 0.f, rv = 0.f;
                if (gcn < N) { mu = mean[b * N + gcn]; rv = rd[b * N + gcn]; }
#pragma unroll
                for (int e = 0; e < 16; e += 2) {
                    int k = seg * 16 + e;
                    float v0 = (Sraw[side][k * 64 + n] - mu) * rv;
                    float v1 = (Sraw[side][(k + 1) * 64 + n] - mu) * rv;
                    unsigned us = bf16r(v0) | (bf16r(v1) << 16);
                    int ui = (n * 64 + k) ^ ((n & 7) << 3);   // ushort-unit XOR swizzle
                    *(unsigned*)(&Xt[side][ui]) = us;
                }
            }
        }
        __syncthreads();
        // MFMA: wave w owns rows [w*16, w*16+16), 4 col-blocks, K-chunks of 32
#pragma unroll
        for (int s = 0; s < 2; ++s) {
            int k0 = s * 32 + (lane >> 4) * 8;
            int acol = w * 16 + (lane & 15);
            short8 af = *(const short8*)(&Xt[0][(acol * 64 + k0) ^ ((acol & 7) << 3)]);
#pragma unroll
            for (int cb = 0; cb < 4; ++cb) {
                int bcol = cb * 16 + (lane & 15);
                short8 bfv = *(const short8*)(&Xt[1][(bcol * 64 + k0) ^ ((bcol & 7) << 3)]);
                acc[cb] = __builtin_amdgcn_mfma_f32_16x16x32_bf16(af, bfv, acc[cb], 0, 0, 0);
            }
        }
        __syncthreads();
    }

    // epilogue: |corr| -> Tr (aliases Sraw, all reads done), then coalesced writes + degree
    float* Tr = &Sraw[0][0];                      // [64][65]
#pragma unroll
    for (int cb = 0; cb < 4; ++cb)
#pragma unroll
        for (int r = 0; r < 4; ++r) {
            int row = w * 16 + (lane >> 4) * 4 + r;   // C/D: col=lane&15, row=(lane>>4)*4+reg
            int col = cb * 16 + (lane & 15);
            Tr[row * 65 + col] = fabsf(acc[cb][r]);
        }
    __syncthreads();

    float* Ab = A + (size_t)b * NN;
    for (int idx = tid; idx < 4096; idx += 256) {
        int il = idx >> 6, jl = idx & 63;
        int ii = i0 + il, jj = j0 + jl;
        if (ii < N && jj < N) Ab[ii * N + jj] = Tr[il * 65 + jl];
    }
    if (tid < 64) {
        int ii = i0 + tid;
        if (ii < N) {
            float s = 0.f;
            int jmax = (j0 + 64 <= N) ? 64 : (N - j0);
            for (int c2 = 0; c2 < jmax; ++c2) s += Tr[tid * 65 + c2];
            atomicAdd(&deg[b * N + ii], s);
        }
    }
    if (i0 != j0) {   // mirrored tile (A symmetric) + its column sums
        for (int idx = tid; idx < 4096; idx += 256) {
            int jl = idx >> 6, il = idx & 63;
            int jj = j0 + jl, ii = i0 + il;
            if (ii < N && jj < N) Ab[jj * N + ii] = Tr[il * 65 + jl];
        }
        if (tid < 64) {
            int jj = j0 + tid;
            if (jj < N) {
                float s = 0.f;
                int imax = (i0 + 64 <= N) ? 64 : (N - i0);
                for (int r2 = 0; r2 < imax; ++r2) s += Tr[r2 * 65 + tid];
                atomicAdd(&deg[b * N + jj], s);
            }
        }
    }
}

// ---------------- K2: dinv = rsqrt(1 + deg) ----------------
__global__ __launch_bounds__(256) void k_dinv2(const float* __restrict__ deg,
                                               float* __restrict__ dinv) {
    int i = blockIdx.x * 256 + threadIdx.x;
    if (i < B * N) dinv[i] = rsqrtf(1.f + deg[i]);
}

// ---------------- K3: fused GCN layer 1 (t1 = A@W1; h = relu(L-apply + b1)) ----------------
__global__ __launch_bounds__(512) void k_gcn1(const float* __restrict__ A,
                                              const float* __restrict__ W1,
                                              const float* __restrict__ b1,
                                              const float* __restrict__ dinv,
                                              float* __restrict__ hout) {
    __shared__ float Ws[N * H];   // W1 [k][l], 51.2 KB
    __shared__ float Ys[N * H];   // dinv ⊙ (A@W1), [j][l]
    int b = blockIdx.x, tid = threadIdx.x;
    for (int idx = tid; idx < N * H; idx += 512) Ws[idx] = W1[idx];
    __syncthreads();
    int lane = tid & 63;
    int w = __builtin_amdgcn_readfirstlane((int)(tid >> 6));
    const float* Ab = A + (size_t)b * NN;
    const float* dv = dinv + b * N;

    // phase 1: Ys[j][l] = dinv[j] * sum_k A[j][k] * W1[k][l]
    for (int g = w; g < 50; g += 8) {
        int j0 = g * 4;
        const float* A0 = Ab + (size_t)(j0 + 0) * N;
        const float* A1 = Ab + (size_t)(j0 + 1) * N;
        const float* A2 = Ab + (size_t)(j0 + 2) * N;
        const float* A3 = Ab + (size_t)(j0 + 3) * N;
        float acc0 = 0.f, acc1 = 0.f, acc2 = 0.f, acc3 = 0.f;
        for (int k = 0; k < N; k += 4) {
            float4 a0 = *(const float4*)(A0 + k);
            float4 a1 = *(const float4*)(A1 + k);
            float4 a2 = *(const float4*)(A2 + k);
            float4 a3 = *(const float4*)(A3 + k);
            float y0 = Ws[(k + 0) * H + lane];
            float y1 = Ws[(k + 1) * H + lane];
            float y2 = Ws[(k + 2) * H + lane];
            float y3 = Ws[(k + 3) * H + lane];
            acc0 += a0.x * y0 + a0.y * y1 + a0.z * y2 + a0.w * y3;
            acc1 += a1.x * y0 + a1.y * y1 + a1.z * y2 + a1.w * y3;
            acc2 += a2.x * y0 + a2.y * y1 + a2.z * y2 + a2.w * y3;
            acc3 += a3.x * y0 + a3.y * y1 + a3.z * y2 + a3.w * y3;
        }
        Ys[(j0 + 0) * H + lane] = dv[j0 + 0] * acc0;
        Ys[(j0 + 1) * H + lane] = dv[j0 + 1] * acc1;
        Ys[(j0 + 2) * H + lane] = dv[j0 + 2] * acc2;
        Ys[(j0 + 3) * H + lane] = dv[j0 + 3] * acc3;
    }
    __syncthreads();
    // phase 2: h = relu(dinv_i * (A@Ys + Ys_i) + b1)
    float bias = b1[lane];
    float* hb = hout + (size_t)b * N * H;
    for (int g = w; g < 50; g += 8) {
        int i0 = g * 4;
        const float* A0 = Ab + (size_t)(i0 + 0) * N;
        const float* A1 = Ab + (size_t)(i0 + 1) * N;
        const float* A2 = Ab + (size_t)(i0 + 2) * N;
        const float* A3 = Ab + (size_t)(i0 + 3) * N;
        float acc0 = 0.f, acc1 = 0.f, acc2 = 0.f, acc3 = 0.f;
        for (int k = 0; k < N; k += 4) {
            float4 a0 = *(const float4*)(A0 + k);
            float4 a1 = *(const float4*)(A1 + k);
            float4 a2 = *(const float4*)(A2 + k);
            float4 a3 = *(const float4*)(A3 + k);
            float y0 = Ys[(k + 0) * H + lane];
            float y1 = Ys[(k + 1) * H + lane];
            float y2 = Ys[(k + 2) * H + lane];
            float y3 = Ys[(k + 3) * H + lane];
            acc0 += a0.x * y0 + a0.y * y1 + a0.z * y2 + a0.w * y3;
            acc1 += a1.x * y0 + a1.y * y1 + a1.z * y2 + a1.w * y3;
            acc2 += a2.x * y0 + a2.y * y1 + a2.z * y2 + a2.w * y3;
            acc3 += a3.x * y0 + a3.y * y1 + a3.z * y2 + a3.w * y3;
        }
        float v0 = dv[i0 + 0] * (acc0 + Ys[(i0 + 0) * H + lane]) + bias;
        float v1 = dv[i0 + 1] * (acc1 + Ys[(i0 + 1) * H + lane]) + bias;
        float v2 = dv[i0 + 2] * (acc2 + Ys[(i0 + 2) * H + lane]) + bias;
        float v3 = dv[i0 + 3] * (acc3 + Ys[(i0 + 3) * H + lane]) + bias;
        hb[(i0 + 0) * H + lane] = fmaxf(v0, 0.f);
        hb[(i0 + 1) * H + lane] = fmaxf(v1, 0.f);
        hb[(i0 + 2) * H + lane] = fmaxf(v2, 0.f);
        hb[(i0 + 3) * H + lane] = fmaxf(v3, 0.f);
    }
}

// ---------------- K4: layer 2 (y2 = dinv⊙(h@W2); out = relu(L-apply + b2)) ----------------
__global__ __launch_bounds__(512) void k_out(const float* __restrict__ A,
                                             const float* __restrict__ dinv,
                                             const float* __restrict__ W2,
                                             const float* __restrict__ b2,
                                             float* __restrict__ out /* in: h, out: final */) {
    __shared__ float Ws[H * H];   // 16.4 KB
    __shared__ float Ys[N * H];   // 51.2 KB
    int b = blockIdx.x, tid = threadIdx.x;
    for (int idx = tid; idx < H * H; idx += 512) Ws[idx] = W2[idx];
    __syncthreads();
    int lane = tid & 63;
    int w = __builtin_amdgcn_readfirstlane((int)(tid >> 6));
    const float* Ab = A + (size_t)b * NN;
    const float* dv = dinv + b * N;
    float* ob = out + (size_t)b * N * H;

    // phase 1: Ys[j][l] = dinv[j] * sum_k h[j][k] * W2[k][l]
    for (int g = w; g < 50; g += 8) {
        int j0 = g * 4;
        const float* H0 = ob + (size_t)(j0 + 0) * H;
        const float* H1 = ob + (size_t)(j0 + 1) * H;
        const float* H2 = ob + (size_t)(j0 + 2) * H;
        const float* H3 = ob + (size_t)(j0 + 3) * H;
        float acc0 = 0.f, acc1 = 0.f, acc2 = 0.f, acc3 = 0.f;
        for (int k = 0; k < H; k += 4) {
            float4 a0 = *(const float4*)(H0 + k);
            float4 a1 = *(const float4*)(H1 + k);
            float4 a2 = *(const float4*)(H2 + k);
            float4 a3 = *(const float4*)(H3 + k);
            float y0 = Ws[(k + 0) * H + lane];
            float y1 = Ws[(k + 1) * H + lane];
            float y2 = Ws[(k + 2) * H + lane];
            float y3 = Ws[(k + 3) * H + lane];
            acc0 += a0.x * y0 + a0.y * y1 + a0.z * y2 + a0.w * y3;
            acc1 += a1.x * y0 + a1.y * y1 + a1.z * y2 + a1.w * y3;
            acc2 += a2.x * y0 + a2.y * y1 + a2.z * y2 + a2.w * y3;
            acc3 += a3.x * y0 + a3.y * y1 + a3.z * y2 + a3.w * y3;
        }
        Ys[(j0 + 0) * H + lane] = dv[j0 + 0] * acc0;
        Ys[(j0 + 1) * H + lane] = dv[j0 + 1] * acc1;
        Ys[(j0 + 2) * H + lane] = dv[j0 + 2] * acc2;
        Ys[(j0 + 3) * H + lane] = dv[j0 + 3] * acc3;
    }
    __syncthreads();
    // phase 2: out = relu(dinv_i * (A@Ys + Ys_i) + b2)
    float bias = b2[lane];
    for (int g = w; g < 50; g += 8) {
        int i0 = g * 4;
        const float* A0 = Ab + (size_t)(i0 + 0) * N;
        const float* A1 = Ab + (size_t)(i0 + 1) * N;
        const float* A2 = Ab + (size_t)(i0 + 2) * N;
        const float* A3 = Ab + (size_t)(i0 + 3) * N;
        float acc0 = 0.f, acc1 = 0.f, acc2 = 0.f, acc3 = 0.f;
        for (int k = 0; k < N; k += 4) {
            float4 a0 = *(const float4*)(A0 + k);
            float4 a1 = *(const float4*)(A1 + k);
            float4 a2 = *(const float4*)(A2 + k);
            float4 a3 = *(const float4*)(A3 + k);
            float y0 = Ys[(k + 0) * H + lane];
            float y1 = Ys[(k + 1) * H + lane];
            float y2 = Ys[(k + 2) * H + lane];
            float y3 = Ys[(k + 3) * H + lane];
            acc0 += a0.x * y0 + a0.y * y1 + a0.z * y2 + a0.w * y3;
            acc1 += a1.x * y0 + a1.y * y1 + a1.z * y2 + a1.w * y3;
            acc2 += a2.x * y0 + a2.y * y1 + a2.z * y2 + a2.w * y3;
            acc3 += a3.x * y0 + a3.y * y1 + a3.z * y2 + a3.w * y3;
        }
        float v0 = dv[i0 + 0] * (acc0 + Ys[(i0 + 0) * H + lane]) + bias;
        float v1 = dv[i0 + 1] * (acc1 + Ys[(i0 + 1) * H + lane]) + bias;
        float v2 = dv[i0 + 2] * (acc2 + Ys[(i0 + 2) * H + lane]) + bias;
        float v3 = dv[i0 + 3] * (acc3 + Ys[(i0 + 3) * H + lane]) + bias;
        ob[(i0 + 0) * H + lane] = fmaxf(v0, 0.f);
        ob[(i0 + 1) * H + lane] = fmaxf(v1, 0.f);
        ob[(i0 + 2) * H + lane] = fmaxf(v2, 0.f);
        ob[(i0 + 3) * H + lane] = fmaxf(v3, 0.f);
    }
}

extern "C" void kernel_launch(void* const* d_in, const int* in_sizes, int n_in,
                              void* d_out, int out_size, void* d_ws, size_t ws_size,
                              hipStream_t stream) {
    const float* data = (const float*)d_in[0];
    const float* W1   = (const float*)d_in[1];
    const float* b1   = (const float*)d_in[2];
    const float* W2   = (const float*)d_in[3];
    const float* b2   = (const float*)d_in[4];
    float* out = (float*)d_out;

    float* ws   = (float*)d_ws;
    float* A    = ws;                         // 20,480,000 floats (81.9 MB)
    float* mean = A + (size_t)B * NN;         // 102,400
    float* rdv  = mean + B * N;               // 102,400
    float* deg  = rdv + B * N;                // 102,400
    float* dinv = deg + B * N;                // 102,400  -> total 83.6 MB

    hipMemsetAsync(deg, 0, (size_t)B * N * sizeof(float), stream);
    hipLaunchKernelGGL(k_stats, dim3(B),       dim3(256), 0, stream, data, mean, rdv);
    hipLaunchKernelGGL(k_corr,  dim3(B * 10),  dim3(256), 0, stream, data, mean, rdv, A, deg);
    hipLaunchKernelGGL(k_dinv2, dim3((B * N + 255) / 256), dim3(256), 0, stream, deg, dinv);
    hipLaunchKernelGGL(k_gcn1,  dim3(B),       dim3(512), 0, stream, A, W1, b1, dinv, out);
    hipLaunchKernelGGL(k_out,   dim3(B),       dim3(512), 0, stream, A, dinv, W2, b2, out);
}

// Round 3
// 145.029 us; speedup vs baseline: 5.3980x; 2.9818x over previous
//
#include <hip/hip_runtime.h>
#include <math.h>

#define B 512
#define T 256
#define N 200
#define H 64
#define TN (T*N)     // 51200

#define ARS 232              // A row stride in bf16 (464 B = 29 x 16B blocks -> conflict-free)
#define ASAMP (N*ARS)        // 46400 bf16 per sample = 92800 B

typedef short short8 __attribute__((ext_vector_type(8)));
typedef float f32x4 __attribute__((ext_vector_type(4)));

__device__ __forceinline__ unsigned bf16r(float x) {
    unsigned u = __float_as_uint(x);
    return (u + 0x7fffu + ((u >> 16) & 1u)) >> 16;   // round-to-nearest-even
}
__device__ __forceinline__ float bf2f(unsigned short u) {
    return __uint_as_float(((unsigned)u) << 16);
}

// ---------------- K0: per-(sample,node) mean and 1/std ----------------
__global__ __launch_bounds__(256) void k_stats(const float* __restrict__ data,
                                               float* __restrict__ mean,
                                               float* __restrict__ rd) {
    int b = blockIdx.x;
    int n = threadIdx.x;
    if (n >= N) return;
    const float* p = data + (size_t)b * TN + n;
    float s = 0.f, ss = 0.f;
#pragma unroll 8
    for (int t = 0; t < T; ++t) {
        float v = p[(size_t)t * N];
        s += v; ss += v * v;
    }
    float mu = s * (1.f / T);
    float var = ss - s * mu;
    mean[b * N + n] = mu;
    rd[b * N + n] = (var > 0.f) ? rsqrtf(var) : 0.f;
}

// ---------------- K1: A = |corr| (bf16 MFMA) -> bf16 padded [200][232] + degree ----------------
__global__ __launch_bounds__(256) void k_corr(const float* __restrict__ data,
                                              const float* __restrict__ mean,
                                              const float* __restrict__ rd,
                                              unsigned short* __restrict__ Abf,
                                              float* __restrict__ deg) {
    int blk = blockIdx.x;
    int x = blk & 7;                  // XCD grouping
    int q = blk >> 3;
    int b = x * 64 + q / 10;
    int t = q - (q / 10) * 10;
    int ti, tj;
    if      (t < 4) { ti = 0; tj = t;     }
    else if (t < 7) { ti = 1; tj = t - 3; }
    else if (t < 9) { ti = 2; tj = t - 5; }
    else            { ti = 3; tj = 3;     }
    int i0 = ti * 64, j0 = tj * 64;

    __shared__ __align__(16) float Sraw[2][4096];            // 32 KB, aliased as Tr later
    __shared__ __align__(16) unsigned short Xt[2][4096];     // 16 KB bf16 [col][k], XOR-swizzled

    int tid = threadIdx.x;
    int lane = tid & 63, w = tid >> 6;
    const float* db = data + (size_t)b * TN;

    f32x4 acc[4] = {};

    for (int c = 0; c < 4; ++c) {                 // 4 chunks of 64 timesteps
        int t0 = c * 64;
        for (int side = 0; side < 2; ++side) {
            int base = side ? j0 : i0;
#pragma unroll
            for (int it = 0; it < 4; ++it) {
                int f = it * 1024 + tid * 4;
                int r = f >> 6, cc = f & 63;
                int gc = base + cc; if (gc > N - 4) gc = N - 4;
                float4 v = *(const float4*)(db + (size_t)(t0 + r) * N + gc);
                *(float4*)(&Sraw[side][f]) = v;
            }
        }
        __syncthreads();
        {
            int n = tid & 63;
            int seg = tid >> 6;
            for (int side = 0; side < 2; ++side) {
                int gcn = (side ? j0 : i0) + n;
                float mu = 0.f, rv = 0.f;
                if (gcn < N) { mu = mean[b * N + gcn]; rv = rd[b * N + gcn]; }
#pragma unroll
                for (int e = 0; e < 16; e += 2) {
                    int k = seg * 16 + e;
                    float v0 = (Sraw[side][k * 64 + n] - mu) * rv;
                    float v1 = (Sraw[side][(k + 1) * 64 + n] - mu) * rv;
                    unsigned us = bf16r(v0) | (bf16r(v1) << 16);
                    int ui = (n * 64 + k) ^ ((n & 7) << 3);
                    *(unsigned*)(&Xt[side][ui]) = us;
                }
            }
        }
        __syncthreads();
#pragma unroll
        for (int s = 0; s < 2; ++s) {
            int k0 = s * 32 + (lane >> 4) * 8;
            int acol = w * 16 + (lane & 15);
            short8 af = *(const short8*)(&Xt[0][(acol * 64 + k0) ^ ((acol & 7) << 3)]);
#pragma unroll
            for (int cb = 0; cb < 4; ++cb) {
                int bcol = cb * 16 + (lane & 15);
                short8 bfv = *(const short8*)(&Xt[1][(bcol * 64 + k0) ^ ((bcol & 7) << 3)]);
                acc[cb] = __builtin_amdgcn_mfma_f32_16x16x32_bf16(af, bfv, acc[cb], 0, 0, 0);
            }
        }
        __syncthreads();
    }

    // epilogue: |corr| -> Tr
    float* Tr = &Sraw[0][0];                      // [64][65]
#pragma unroll
    for (int cb = 0; cb < 4; ++cb)
#pragma unroll
        for (int r = 0; r < 4; ++r) {
            int row = w * 16 + (lane >> 4) * 4 + r;
            int col = cb * 16 + (lane & 15);
            Tr[row * 65 + col] = fabsf(acc[cb][r]);
        }
    __syncthreads();

    unsigned short* Ag = Abf + (size_t)b * ASAMP;

    // direct tile -> bf16 packed (incl. zero pad cols up to 231)
    {
        int nrow = 200 - i0; if (nrow > 64) nrow = 64;
        int ncp = (ARS - j0) >> 1; if (ncp > 32) ncp = 32;
        int jp = tid & 31;
        for (int il = tid >> 5; il < nrow; il += 8) {
            if (jp < ncp) {
                int jj0 = j0 + 2 * jp;
                int ii = i0 + il;
                float v0 = (jj0     < 200) ? Tr[il * 65 + 2 * jp    ] : 0.f;
                float v1 = (jj0 + 1 < 200) ? Tr[il * 65 + 2 * jp + 1] : 0.f;
                unsigned pk = bf16r(v0) | (bf16r(v1) << 16);
                *(unsigned*)(Ag + (size_t)ii * ARS + jj0) = pk;
            }
        }
        if (tid < 64) {
            int ii = i0 + tid;
            if (ii < 200) {
                float s = 0.f; int jmax = 200 - j0; if (jmax > 64) jmax = 64;
                for (int c2 = 0; c2 < jmax; ++c2) s += Tr[tid * 65 + c2];
                atomicAdd(&deg[b * N + ii], s);
            }
        }
    }
    if (i0 != j0) {   // mirrored tile
        int nrw = 200 - j0; if (nrw > 64) nrw = 64;
        int ip = tid & 31;
        for (int jl = tid >> 5; jl < nrw; jl += 8) {
            int ii0 = i0 + 2 * ip;
            float v0 = Tr[(2 * ip) * 65 + jl];
            float v1 = Tr[(2 * ip + 1) * 65 + jl];
            unsigned pk = bf16r(v0) | (bf16r(v1) << 16);
            *(unsigned*)(Ag + (size_t)(j0 + jl) * ARS + ii0) = pk;
        }
        if (tid < 64) {
            int jj = j0 + tid;
            if (jj < 200) {
                float s = 0.f;
                for (int r2 = 0; r2 < 64; ++r2) s += Tr[r2 * 65 + tid];
                atomicAdd(&deg[b * N + jj], s);
            }
        }
    }
}

// ---------------- K2: dinv = rsqrt(1 + deg) ----------------
__global__ __launch_bounds__(256) void k_dinv2(const float* __restrict__ deg,
                                               float* __restrict__ dinv) {
    int i = blockIdx.x * 256 + threadIdx.x;
    if (i < B * N) dinv[i] = rsqrtf(1.f + deg[i]);
}

// ---------------- K3: fused full GCN (both layers) via bf16 MFMA, A resident in LDS ----------------
#define OFF_A    0
#define OFF_YT   92800
#define OFF_BUF2 122496
#define OFF_W2T  152192
#define OFF_DINV 161408
#define OFF_B1   162208
#define OFF_B2   162464
#define LDS_SZ   162720

__device__ __forceinline__ void gemm4(const unsigned char* LDSp, int aA,
                                      int bA0, int bA1, int bA2, int bA3,
                                      int nCh, f32x4* acc) {
    for (int s = 0; s < nCh; ++s) {
        int ko = s * 64;
        short8 av = *(const short8*)(LDSp + aA + ko);
        acc[0] = __builtin_amdgcn_mfma_f32_16x16x32_bf16(av, *(const short8*)(LDSp + bA0 + ko), acc[0], 0, 0, 0);
        acc[1] = __builtin_amdgcn_mfma_f32_16x16x32_bf16(av, *(const short8*)(LDSp + bA1 + ko), acc[1], 0, 0, 0);
        acc[2] = __builtin_amdgcn_mfma_f32_16x16x32_bf16(av, *(const short8*)(LDSp + bA2 + ko), acc[2], 0, 0, 0);
        acc[3] = __builtin_amdgcn_mfma_f32_16x16x32_bf16(av, *(const short8*)(LDSp + bA3 + ko), acc[3], 0, 0, 0);
    }
}

__global__ __launch_bounds__(512) void k_gcn(const unsigned short* __restrict__ Abf,
                                             const float* __restrict__ W1,
                                             const float* __restrict__ b1,
                                             const float* __restrict__ W2,
                                             const float* __restrict__ b2,
                                             const float* __restrict__ dinv,
                                             float* __restrict__ out) {
    __shared__ __align__(16) unsigned char LDS[LDS_SZ];
    const int tid = threadIdx.x;
    const int b = blockIdx.x;
    const int lane = tid & 63;
    const int l15 = lane & 15;
    const int hi = lane >> 4;
    const int wid = tid >> 6;

    // ---- stage ----
    {   // A: linear 92800-byte copy (global layout == LDS layout)
        const uint4* gs = (const uint4*)(Abf + (size_t)b * ASAMP);
        uint4* dv4 = (uint4*)(LDS + OFF_A);
        for (int u = tid; u < 5800; u += 512) dv4[u] = gs[u];
    }
    // W1^T bf16 [l][k], stride 464 B
    for (int e = tid; e < N * H; e += 512) {
        int k = e >> 6, l = e & 63;
        *(unsigned short*)(LDS + OFF_BUF2 + l * 464 + k * 2) = (unsigned short)bf16r(W1[e]);
    }
    // zero pads: W1T k=200..231 and Yt k=200..231
    for (int e = tid; e < 64 * 16; e += 512) {
        int l = e >> 4, d = e & 15;
        *(unsigned*)(LDS + OFF_BUF2 + l * 464 + 400 + d * 4) = 0;
        *(unsigned*)(LDS + OFF_YT + l * 464 + 400 + d * 4) = 0;
    }
    // W2^T bf16 [l][k], stride 144 B
    for (int e = tid; e < H * H; e += 512) {
        int k = e >> 6, l = e & 63;
        *(unsigned short*)(LDS + OFF_W2T + l * 144 + k * 2) = (unsigned short)bf16r(W2[e]);
    }
    if (tid < 200) *(float*)(LDS + OFF_DINV + tid * 4) = dinv[b * N + tid];
    if (tid < 64) *(float*)(LDS + OFF_B1 + tid * 4) = b1[tid];
    else if (tid < 128) *(float*)(LDS + OFF_B2 + (tid - 64) * 4) = b2[tid - 64];
    __syncthreads();

    // ---- G1: t1 = A @ W1; y = dinv*t1 -> Yt (bf16 [l][j]) ----
    for (int rt = wid; rt < 13; rt += 8) {
        int row = rt * 16 + l15; int rowc = (row < 200) ? row : 199;
        f32x4 acc[4] = {};
        gemm4(LDS, OFF_A + rowc * 464 + hi * 16,
              OFF_BUF2 + (l15) * 464 + hi * 16,
              OFF_BUF2 + (16 + l15) * 464 + hi * 16,
              OFF_BUF2 + (32 + l15) * 464 + hi * 16,
              OFF_BUF2 + (48 + l15) * 464 + hi * 16, 7, acc);
        int j0 = rt * 16 + hi * 4;
        if (j0 < 200) {
            float d0 = *(const float*)(LDS + OFF_DINV + (j0 + 0) * 4);
            float d1 = *(const float*)(LDS + OFF_DINV + (j0 + 1) * 4);
            float d2 = *(const float*)(LDS + OFF_DINV + (j0 + 2) * 4);
            float d3 = *(const float*)(LDS + OFF_DINV + (j0 + 3) * 4);
#pragma unroll
            for (int ct = 0; ct < 4; ++ct) {
                int c = ct * 16 + l15;
                unsigned u0 = bf16r(d0 * acc[ct][0]) | (bf16r(d1 * acc[ct][1]) << 16);
                unsigned u1 = bf16r(d2 * acc[ct][2]) | (bf16r(d3 * acc[ct][3]) << 16);
                uint2 uu; uu.x = u0; uu.y = u1;
                *(uint2*)(LDS + OFF_YT + c * 464 + j0 * 2) = uu;
            }
        }
    }
    __syncthreads();

    // ---- G2: z = A @ y; h = relu(dinv_i*(z + y_i) + b1) -> BUF2 (bf16 [i][c], stride 144) ----
    for (int rt = wid; rt < 13; rt += 8) {
        int row = rt * 16 + l15; int rowc = (row < 200) ? row : 199;
        f32x4 acc[4] = {};
        gemm4(LDS, OFF_A + rowc * 464 + hi * 16,
              OFF_YT + (l15) * 464 + hi * 16,
              OFF_YT + (16 + l15) * 464 + hi * 16,
              OFF_YT + (32 + l15) * 464 + hi * 16,
              OFF_YT + (48 + l15) * 464 + hi * 16, 7, acc);
#pragma unroll
        for (int ct = 0; ct < 4; ++ct) {
            int c = ct * 16 + l15;
            float bias = *(const float*)(LDS + OFF_B1 + c * 4);
#pragma unroll
            for (int r = 0; r < 4; ++r) {
                int i = rt * 16 + hi * 4 + r;
                if (i < 200) {
                    float dv = *(const float*)(LDS + OFF_DINV + i * 4);
                    float yi = bf2f(*(const unsigned short*)(LDS + OFF_YT + c * 464 + i * 2));
                    float v = dv * (acc[ct][r] + yi) + bias;
                    *(unsigned short*)(LDS + OFF_BUF2 + i * 144 + c * 2) =
                        (unsigned short)bf16r(fmaxf(v, 0.f));
                }
            }
        }
    }
    __syncthreads();

    // ---- G3: t2 = h @ W2; y2 = dinv*t2 -> Yt ----
    for (int rt = wid; rt < 13; rt += 8) {
        int row = rt * 16 + l15; int rowc = (row < 200) ? row : 199;
        f32x4 acc[4] = {};
        gemm4(LDS, OFF_BUF2 + rowc * 144 + hi * 16,
              OFF_W2T + (l15) * 144 + hi * 16,
              OFF_W2T + (16 + l15) * 144 + hi * 16,
              OFF_W2T + (32 + l15) * 144 + hi * 16,
              OFF_W2T + (48 + l15) * 144 + hi * 16, 2, acc);
        int j0 = rt * 16 + hi * 4;
        if (j0 < 200) {
            float d0 = *(const float*)(LDS + OFF_DINV + (j0 + 0) * 4);
            float d1 = *(const float*)(LDS + OFF_DINV + (j0 + 1) * 4);
            float d2 = *(const float*)(LDS + OFF_DINV + (j0 + 2) * 4);
            float d3 = *(const float*)(LDS + OFF_DINV + (j0 + 3) * 4);
#pragma unroll
            for (int ct = 0; ct < 4; ++ct) {
                int c = ct * 16 + l15;
                unsigned u0 = bf16r(d0 * acc[ct][0]) | (bf16r(d1 * acc[ct][1]) << 16);
                unsigned u1 = bf16r(d2 * acc[ct][2]) | (bf16r(d3 * acc[ct][3]) << 16);
                uint2 uu; uu.x = u0; uu.y = u1;
                *(uint2*)(LDS + OFF_YT + c * 464 + j0 * 2) = uu;
            }
        }
    }
    __syncthreads();

    // ---- G4: z2 = A @ y2; out = relu(dinv_i*(z2 + y2_i) + b2) ----
    for (int rt = wid; rt < 13; rt += 8) {
        int row = rt * 16 + l15; int rowc = (row < 200) ? row : 199;
        f32x4 acc[4] = {};
        gemm4(LDS, OFF_A + rowc * 464 + hi * 16,
              OFF_YT + (l15) * 464 + hi * 16,
              OFF_YT + (16 + l15) * 464 + hi * 16,
              OFF_YT + (32 + l15) * 464 + hi * 16,
              OFF_YT + (48 + l15) * 464 + hi * 16, 7, acc);
#pragma unroll
        for (int ct = 0; ct < 4; ++ct) {
            int c = ct * 16 + l15;
            float bias = *(const float*)(LDS + OFF_B2 + c * 4);
#pragma unroll
            for (int r = 0; r < 4; ++r) {
                int i = rt * 16 + hi * 4 + r;
                if (i < 200) {
                    float dv = *(const float*)(LDS + OFF_DINV + i * 4);
                    float yi = bf2f(*(const unsigned short*)(LDS + OFF_YT + c * 464 + i * 2));
                    float v = dv * (acc[ct][r] + yi) + bias;
                    out[((size_t)b * N + i) * H + c] = fmaxf(v, 0.f);
                }
            }
        }
    }
}

extern "C" void kernel_launch(void* const* d_in, const int* in_sizes, int n_in,
                              void* d_out, int out_size, void* d_ws, size_t ws_size,
                              hipStream_t stream) {
    const float* data = (const float*)d_in[0];
    const float* W1   = (const float*)d_in[1];
    const float* b1   = (const float*)d_in[2];
    const float* W2   = (const float*)d_in[3];
    const float* b2   = (const float*)d_in[4];
    float* out = (float*)d_out;

    unsigned short* Abf = (unsigned short*)d_ws;          // 512*46400 bf16 = 47.5 MB
    float* mean = (float*)(Abf + (size_t)B * ASAMP);      // 102400 f32
    float* rdv  = mean + B * N;
    float* deg  = rdv + B * N;
    float* dinv = deg + B * N;                            // total ~49.2 MB

    hipMemsetAsync(deg, 0, (size_t)B * N * sizeof(float), stream);
    hipLaunchKernelGGL(k_stats, dim3(B),      dim3(256), 0, stream, data, mean, rdv);
    hipLaunchKernelGGL(k_corr,  dim3(B * 10), dim3(256), 0, stream, data, mean, rdv, Abf, deg);
    hipLaunchKernelGGL(k_dinv2, dim3((B * N + 255) / 256), dim3(256), 0, stream, deg, dinv);
    hipLaunchKernelGGL(k_gcn,   dim3(B),      dim3(512), 0, stream, Abf, W1, b1, W2, b2, dinv, out);
}

// Round 5
// 118.164 us; speedup vs baseline: 6.6253x; 1.2273x over previous
//
#include <hip/hip_runtime.h>
#include <hip/hip_fp16.h>
#include <math.h>

#define B 512
#define T 256
#define N 200
#define H 64
#define TN (T*N)     // 51200

#define ARS 232              // A row stride in bf16 (464 B)
#define ASAMP (N*ARS)        // 46400 bf16 per sample = 92800 B

typedef short short8 __attribute__((ext_vector_type(8)));
typedef float f32x4 __attribute__((ext_vector_type(4)));
typedef float f32x16 __attribute__((ext_vector_type(16)));

__device__ __forceinline__ unsigned bf16r(float x) {
    unsigned u = __float_as_uint(x);
    return (u + 0x7fffu + ((u >> 16) & 1u)) >> 16;   // round-to-nearest-even
}
__device__ __forceinline__ float bf2f(unsigned short u) {
    return __uint_as_float(((unsigned)u) << 16);
}
__device__ __forceinline__ unsigned f2h(float x) {
    return (unsigned)__half_as_ushort(__float2half(x));
}
__device__ __forceinline__ float h2f(unsigned short u) {
    return __half2float(__ushort_as_half(u));
}

// ================= K1: per-sample |corr| -> bf16 A[200][232] + dinv =================
// LDS map (bytes):
//  [0,      102400)  X: [200 nodes][256 t] 2B/elem, row stride 512B,
//                    16B-block XOR swizzle ((n&31)<<4). Phase A: raw fp16;
//                    phase B: normalized bf16. After MFMA: first 92,800 B
//                    reused as A-out [200][232] bf16 LINEAR (global image).
//  [102400, 129536)  Sraw: [32 t][212 n] fp32 staging chunk
//  [129536, 130336)  mu[200] f32
//  [130336, 131136)  rs[200] f32
__global__ __launch_bounds__(512) void k_corr(const float* __restrict__ data,
                                              unsigned short* __restrict__ Abf,
                                              float* __restrict__ dinv) {
    __shared__ __align__(16) unsigned char LDS[131136];
    float* SrawF = (float*)(LDS + 102400);
    float* muA   = (float*)(LDS + 129536);
    float* rsA   = (float*)(LDS + 130336);

    const int tid  = threadIdx.x;
    const int b    = blockIdx.x;
    const int lane = tid & 63;
    const int wid  = tid >> 6;
    const int l31  = lane & 31;
    const int hi   = lane >> 5;
    const float4* db4 = (const float4*)(data + (size_t)b * TN);

    // ---- phase 1: stage raw data, transpose to fp16 X[n][t] (8 chunks of 32 t) ----
    for (int c = 0; c < 8; ++c) {
#pragma unroll
        for (int i = 0; i < 4; ++i) {
            int idx = tid + i * 512;
            if (idx < 1600) {
                int t = idx / 50, n4 = idx % 50;
                *(float4*)(&SrawF[t * 212 + n4 * 4]) = db4[c * 1600 + idx];
            }
        }
        __syncthreads();
#pragma unroll
        for (int i = 0; i < 4; ++i) {
            int e = tid + i * 512;
            if (e < 1600) {
                int n = e % 200, q = e / 200;            // q: t-quad within chunk
                float v0 = SrawF[(q * 4 + 0) * 212 + n];
                float v1 = SrawF[(q * 4 + 1) * 212 + n];
                float v2 = SrawF[(q * 4 + 2) * 212 + n];
                float v3 = SrawF[(q * 4 + 3) * 212 + n];
                uint2 pk;
                pk.x = f2h(v0) | (f2h(v1) << 16);
                pk.y = f2h(v2) | (f2h(v3) << 16);
                int base = c * 64 + q * 8;               // byte offset in row (8B aligned)
                *(uint2*)(LDS + n * 512 + (base ^ ((n & 31) << 4))) = pk;
            }
        }
        __syncthreads();
    }

    // ---- phase 2: per-node stats (order-independent: read row linearly) ----
    if (tid < 200) {
        float s = 0.f, ss = 0.f;
#pragma unroll 4
        for (int blk = 0; blk < 32; ++blk) {
            short8 v = *(const short8*)(LDS + tid * 512 + blk * 16);
#pragma unroll
            for (int e = 0; e < 8; ++e) {
                float f = h2f((unsigned short)v[e]);
                s += f; ss += f * f;
            }
        }
        float mu = s * (1.f / T);
        float var = ss - s * mu;
        muA[tid] = mu;
        rsA[tid] = (var > 0.f) ? rsqrtf(var) : 0.f;
    }
    __syncthreads();

    // ---- phase 3: normalize in place fp16 -> bf16 (in-place: traversal-agnostic) ----
#pragma unroll 4
    for (int i = 0; i < 25; ++i) {
        int e = tid + i * 512;                           // 12800 uint2 = 25*512 exactly
        int n = e % 200, q = e / 200;                    // row n always owns its 512B
        uint2* p = (uint2*)(LDS + n * 512 + q * 8);
        uint2 v = *p;
        float m = muA[n], r = rsA[n];
        float f0 = (h2f((unsigned short)(v.x & 0xffff)) - m) * r;
        float f1 = (h2f((unsigned short)(v.x >> 16)) - m) * r;
        float f2 = (h2f((unsigned short)(v.y & 0xffff)) - m) * r;
        float f3 = (h2f((unsigned short)(v.y >> 16)) - m) * r;
        v.x = bf16r(f0) | (bf16r(f1) << 16);
        v.y = bf16r(f2) | (bf16r(f3) << 16);
        *p = v;
    }
    __syncthreads();

    // ---- phase 4: corr MFMA, 32x32x16, wave = row-panel, 7 col-tiles ----
    f32x16 acc[7] = {};
    if (wid < 7) {
        int arow = wid * 32 + l31; if (arow > 199) arow = 199;
        const int aswz = (arow & 31) << 4;
        int bc[7], bswz[7];
#pragma unroll
        for (int ct = 0; ct < 7; ++ct) {
            int c2 = ct * 32 + l31; if (c2 > 199) c2 = 199;
            bc[ct] = c2; bswz[ct] = (c2 & 31) << 4;
        }
#pragma unroll 2
        for (int kc = 0; kc < 16; ++kc) {
            int kb = kc * 32 + hi * 16;
            short8 a = *(const short8*)(LDS + arow * 512 + (kb ^ aswz));
#pragma unroll
            for (int ct = 0; ct < 7; ++ct) {
                short8 bb = *(const short8*)(LDS + bc[ct] * 512 + (kb ^ bswz[ct]));
                acc[ct] = __builtin_amdgcn_mfma_f32_32x32x16_bf16(a, bb, acc[ct], 0, 0, 0);
            }
        }
    }
    __syncthreads();     // X dead; reuse LDS[0..92800) as A image

    // ---- phase 5: dump |acc| -> A[200][232] bf16 linear + zero pads ----
    unsigned short* A16 = (unsigned short*)LDS;
    if (wid < 7) {
#pragma unroll
        for (int ct = 0; ct < 7; ++ct) {
            int col = ct * 32 + l31;
            if (col < 200) {
#pragma unroll
                for (int r = 0; r < 16; ++r) {
                    int row = wid * 32 + (r & 3) + 8 * (r >> 2) + 4 * hi;
                    if (row < 200)
                        A16[row * ARS + col] = (unsigned short)bf16r(fabsf(acc[ct][r]));
                }
            }
        }
    }
    // pad cols 200..231 = 0  (FULL 64-byte range [400,464) per row — round-4 bug
    // was pc<8 which left elements 216..231 as stale X data, corrupting dinv)
    for (int e = tid; e < 3200; e += 512) {
        int row = e >> 4, pc = e & 15;
        *(unsigned*)(LDS + row * 464 + 400 + pc * 4) = 0;
    }
    __syncthreads();

    // ---- phase 6: row sums -> dinv; coalesced A copy-out ----
    if (tid < 200) {
        float s = 1.f;                                   // the +I
#pragma unroll 4
        for (int e2 = 0; e2 < 29; ++e2) {
            short8 v = *(const short8*)(LDS + tid * 464 + e2 * 16);
#pragma unroll
            for (int j = 0; j < 8; ++j) s += bf2f((unsigned short)v[j]);
        }
        dinv[b * N + tid] = rsqrtf(s);
    }
    {
        const uint4* s4 = (const uint4*)LDS;
        uint4* g4 = (uint4*)(Abf + (size_t)b * ASAMP);
        for (int u = tid; u < 5800; u += 512) g4[u] = s4[u];
    }
}

// ================= K2: fused full GCN =================
#define OFF_A    0
#define OFF_YT   92800
#define OFF_BUF2 122496
#define OFF_W2T  152192
#define OFF_DINV 161408
#define OFF_B1   162208
#define OFF_B2   162464
#define LDS_SZ   162720

__device__ __forceinline__ void gemm4(const unsigned char* LDSp, int aA,
                                      int bA0, int bA1, int bA2, int bA3,
                                      int nCh, f32x4* acc) {
    for (int s = 0; s < nCh; ++s) {
        int ko = s * 64;
        short8 av = *(const short8*)(LDSp + aA + ko);
        acc[0] = __builtin_amdgcn_mfma_f32_16x16x32_bf16(av, *(const short8*)(LDSp + bA0 + ko), acc[0], 0, 0, 0);
        acc[1] = __builtin_amdgcn_mfma_f32_16x16x32_bf16(av, *(const short8*)(LDSp + bA1 + ko), acc[1], 0, 0, 0);
        acc[2] = __builtin_amdgcn_mfma_f32_16x16x32_bf16(av, *(const short8*)(LDSp + bA2 + ko), acc[2], 0, 0, 0);
        acc[3] = __builtin_amdgcn_mfma_f32_16x16x32_bf16(av, *(const short8*)(LDSp + bA3 + ko), acc[3], 0, 0, 0);
    }
}

__global__ __launch_bounds__(512) void k_gcn(const unsigned short* __restrict__ Abf,
                                             const float* __restrict__ W1,
                                             const float* __restrict__ b1,
                                             const float* __restrict__ W2,
                                             const float* __restrict__ b2,
                                             const float* __restrict__ dinv,
                                             float* __restrict__ out) {
    __shared__ __align__(16) unsigned char LDS[LDS_SZ];
    const int tid = threadIdx.x;
    const int b = blockIdx.x;
    const int lane = tid & 63;
    const int l15 = lane & 15;
    const int hi = lane >> 4;
    const int wid = tid >> 6;

    // ---- stage ----
    {
        const uint4* gs = (const uint4*)(Abf + (size_t)b * ASAMP);
        uint4* dv4 = (uint4*)(LDS + OFF_A);
        for (int u = tid; u < 5800; u += 512) dv4[u] = gs[u];
    }
    for (int e = tid; e < N * H; e += 512) {
        int k = e >> 6, l = e & 63;
        *(unsigned short*)(LDS + OFF_BUF2 + l * 464 + k * 2) = (unsigned short)bf16r(W1[e]);
    }
    for (int e = tid; e < 64 * 16; e += 512) {
        int l = e >> 4, d = e & 15;
        *(unsigned*)(LDS + OFF_BUF2 + l * 464 + 400 + d * 4) = 0;
        *(unsigned*)(LDS + OFF_YT + l * 464 + 400 + d * 4) = 0;
    }
    for (int e = tid; e < H * H; e += 512) {
        int k = e >> 6, l = e & 63;
        *(unsigned short*)(LDS + OFF_W2T + l * 144 + k * 2) = (unsigned short)bf16r(W2[e]);
    }
    if (tid < 200) *(float*)(LDS + OFF_DINV + tid * 4) = dinv[b * N + tid];
    if (tid < 64) *(float*)(LDS + OFF_B1 + tid * 4) = b1[tid];
    else if (tid < 128) *(float*)(LDS + OFF_B2 + (tid - 64) * 4) = b2[tid - 64];
    __syncthreads();

    // ---- G1: t1 = A @ W1; y = dinv*t1 -> Yt (bf16 [l][j]) ----
    for (int rt = wid; rt < 13; rt += 8) {
        int row = rt * 16 + l15; int rowc = (row < 200) ? row : 199;
        f32x4 acc[4] = {};
        gemm4(LDS, OFF_A + rowc * 464 + hi * 16,
              OFF_BUF2 + (l15) * 464 + hi * 16,
              OFF_BUF2 + (16 + l15) * 464 + hi * 16,
              OFF_BUF2 + (32 + l15) * 464 + hi * 16,
              OFF_BUF2 + (48 + l15) * 464 + hi * 16, 7, acc);
        int j0 = rt * 16 + hi * 4;
        if (j0 < 200) {
            float d0 = *(const float*)(LDS + OFF_DINV + (j0 + 0) * 4);
            float d1 = *(const float*)(LDS + OFF_DINV + (j0 + 1) * 4);
            float d2 = *(const float*)(LDS + OFF_DINV + (j0 + 2) * 4);
            float d3 = *(const float*)(LDS + OFF_DINV + (j0 + 3) * 4);
#pragma unroll
            for (int ct = 0; ct < 4; ++ct) {
                int c = ct * 16 + l15;
                unsigned u0 = bf16r(d0 * acc[ct][0]) | (bf16r(d1 * acc[ct][1]) << 16);
                unsigned u1 = bf16r(d2 * acc[ct][2]) | (bf16r(d3 * acc[ct][3]) << 16);
                uint2 uu; uu.x = u0; uu.y = u1;
                *(uint2*)(LDS + OFF_YT + c * 464 + j0 * 2) = uu;
            }
        }
    }
    __syncthreads();

    // ---- G2: z = A @ y; h = relu(dinv_i*(z + y_i) + b1) -> BUF2 ----
    for (int rt = wid; rt < 13; rt += 8) {
        int row = rt * 16 + l15; int rowc = (row < 200) ? row : 199;
        f32x4 acc[4] = {};
        gemm4(LDS, OFF_A + rowc * 464 + hi * 16,
              OFF_YT + (l15) * 464 + hi * 16,
              OFF_YT + (16 + l15) * 464 + hi * 16,
              OFF_YT + (32 + l15) * 464 + hi * 16,
              OFF_YT + (48 + l15) * 464 + hi * 16, 7, acc);
#pragma unroll
        for (int ct = 0; ct < 4; ++ct) {
            int c = ct * 16 + l15;
            float bias = *(const float*)(LDS + OFF_B1 + c * 4);
#pragma unroll
            for (int r = 0; r < 4; ++r) {
                int i = rt * 16 + hi * 4 + r;
                if (i < 200) {
                    float dv = *(const float*)(LDS + OFF_DINV + i * 4);
                    float yi = bf2f(*(const unsigned short*)(LDS + OFF_YT + c * 464 + i * 2));
                    float v = dv * (acc[ct][r] + yi) + bias;
                    *(unsigned short*)(LDS + OFF_BUF2 + i * 144 + c * 2) =
                        (unsigned short)bf16r(fmaxf(v, 0.f));
                }
            }
        }
    }
    __syncthreads();

    // ---- G3: t2 = h @ W2; y2 = dinv*t2 -> Yt ----
    for (int rt = wid; rt < 13; rt += 8) {
        int row = rt * 16 + l15; int rowc = (row < 200) ? row : 199;
        f32x4 acc[4] = {};
        gemm4(LDS, OFF_BUF2 + rowc * 144 + hi * 16,
              OFF_W2T + (l15) * 144 + hi * 16,
              OFF_W2T + (16 + l15) * 144 + hi * 16,
              OFF_W2T + (32 + l15) * 144 + hi * 16,
              OFF_W2T + (48 + l15) * 144 + hi * 16, 2, acc);
        int j0 = rt * 16 + hi * 4;
        if (j0 < 200) {
            float d0 = *(const float*)(LDS + OFF_DINV + (j0 + 0) * 4);
            float d1 = *(const float*)(LDS + OFF_DINV + (j0 + 1) * 4);
            float d2 = *(const float*)(LDS + OFF_DINV + (j0 + 2) * 4);
            float d3 = *(const float*)(LDS + OFF_DINV + (j0 + 3) * 4);
#pragma unroll
            for (int ct = 0; ct < 4; ++ct) {
                int c = ct * 16 + l15;
                unsigned u0 = bf16r(d0 * acc[ct][0]) | (bf16r(d1 * acc[ct][1]) << 16);
                unsigned u1 = bf16r(d2 * acc[ct][2]) | (bf16r(d3 * acc[ct][3]) << 16);
                uint2 uu; uu.x = u0; uu.y = u1;
                *(uint2*)(LDS + OFF_YT + c * 464 + j0 * 2) = uu;
            }
        }
    }
    __syncthreads();

    // ---- G4: z2 = A @ y2; out = relu(dinv_i*(z2 + y2_i) + b2) ----
    for (int rt = wid; rt < 13; rt += 8) {
        int row = rt * 16 + l15; int rowc = (row < 200) ? row : 199;
        f32x4 acc[4] = {};
        gemm4(LDS, OFF_A + rowc * 464 + hi * 16,
              OFF_YT + (l15) * 464 + hi * 16,
              OFF_YT + (16 + l15) * 464 + hi * 16,
              OFF_YT + (32 + l15) * 464 + hi * 16,
              OFF_YT + (48 + l15) * 464 + hi * 16, 7, acc);
#pragma unroll
        for (int ct = 0; ct < 4; ++ct) {
            int c = ct * 16 + l15;
            float bias = *(const float*)(LDS + OFF_B2 + c * 4);
#pragma unroll
            for (int r = 0; r < 4; ++r) {
                int i = rt * 16 + hi * 4 + r;
                if (i < 200) {
                    float dv = *(const float*)(LDS + OFF_DINV + i * 4);
                    float yi = bf2f(*(const unsigned short*)(LDS + OFF_YT + c * 464 + i * 2));
                    float v = dv * (acc[ct][r] + yi) + bias;
                    out[((size_t)b * N + i) * H + c] = fmaxf(v, 0.f);
                }
            }
        }
    }
}

extern "C" void kernel_launch(void* const* d_in, const int* in_sizes, int n_in,
                              void* d_out, int out_size, void* d_ws, size_t ws_size,
                              hipStream_t stream) {
    const float* data = (const float*)d_in[0];
    const float* W1   = (const float*)d_in[1];
    const float* b1   = (const float*)d_in[2];
    const float* W2   = (const float*)d_in[3];
    const float* b2   = (const float*)d_in[4];
    float* out = (float*)d_out;

    unsigned short* Abf = (unsigned short*)d_ws;          // 512*46400 bf16 = 47.5 MB
    float* dinv = (float*)(Abf + (size_t)B * ASAMP);      // 102400 f32 -> total ~47.9 MB

    hipLaunchKernelGGL(k_corr, dim3(B), dim3(512), 0, stream, data, Abf, dinv);
    hipLaunchKernelGGL(k_gcn,  dim3(B), dim3(512), 0, stream, Abf, W1, b1, W2, b2, dinv, out);
}

// Round 6
// 98.700 us; speedup vs baseline: 7.9318x; 1.1972x over previous
//
#include <hip/hip_runtime.h>
#include <hip/hip_fp16.h>
#include <math.h>

#define B 512
#define T 256
#define N 200
#define H 64
#define TN (T*N)     // 51200

#define ARS 232              // A row stride in bf16 (464 B)
#define ASAMP (N*ARS)        // 46400 bf16 per sample = 92800 B

#define XRS 528              // X row stride in BYTES (33*16B; 33%8==1 -> natural bank skew)

typedef short short8 __attribute__((ext_vector_type(8)));
typedef float f32x4 __attribute__((ext_vector_type(4)));
typedef float f32x16 __attribute__((ext_vector_type(16)));

__device__ __forceinline__ unsigned bf16r(float x) {
    unsigned u = __float_as_uint(x);
    return (u + 0x7fffu + ((u >> 16) & 1u)) >> 16;   // round-to-nearest-even
}
__device__ __forceinline__ float bf2f(unsigned short u) {
    return __uint_as_float(((unsigned)u) << 16);
}
__device__ __forceinline__ unsigned f2h(float x) {
    return (unsigned)__half_as_ushort(__float2half(x));
}
__device__ __forceinline__ float h2f(unsigned short u) {
    return __half2float(__ushort_as_half(u));
}
__device__ __forceinline__ unsigned norm2(unsigned v, float m, float r) {
    float f0 = (h2f((unsigned short)(v & 0xffff)) - m) * r;
    float f1 = (h2f((unsigned short)(v >> 16)) - m) * r;
    return bf16r(f0) | (bf16r(f1) << 16);
}

// ================= K1: per-sample |corr| -> bf16 A[200][232] + dinv =================
// LDS map (bytes):
//  [0,      105600)  X: [200 nodes][256 t] 2B/elem, row stride 528B (NO xor swizzle;
//                    33x16B rows give slot skew 1 mod 8 -> all row-parallel 16B
//                    accesses are bank-conflict-free). Phase A: raw fp16; phase B:
//                    normalized bf16. After MFMA: first 92,800 B reused as A-out
//                    [200][232] bf16 LINEAR (global image, row stride 464B; 29%8==5
//                    -> also conflict-free).
//  [105600, 132736)  Sraw: [32 t][212 n] fp32 staging chunk
//  [132736, 133536)  mu[200] f32
//  [133536, 134336)  rs[200] f32
__global__ __launch_bounds__(512) void k_corr(const float* __restrict__ data,
                                              unsigned short* __restrict__ Abf,
                                              float* __restrict__ dinv) {
    __shared__ __align__(16) unsigned char LDS[134336];
    float* SrawF = (float*)(LDS + 105600);
    float* muA   = (float*)(LDS + 132736);
    float* rsA   = (float*)(LDS + 133536);

    const int tid  = threadIdx.x;
    const int b    = blockIdx.x;
    const int lane = tid & 63;
    const int wid  = tid >> 6;
    const int l31  = lane & 31;
    const int hi   = lane >> 5;
    const float4* db4 = (const float4*)(data + (size_t)b * TN);

    // ---- phase 1: stage raw data, transpose to fp16 X[n][t] (8 chunks of 32 t) ----
    for (int c = 0; c < 8; ++c) {
#pragma unroll
        for (int i = 0; i < 4; ++i) {
            int idx = tid + i * 512;
            if (idx < 1600) {
                int t = idx / 50, n4 = idx % 50;
                *(float4*)(&SrawF[t * 212 + n4 * 4]) = db4[c * 1600 + idx];
            }
        }
        __syncthreads();
        // 800 units: (n, q) -> pack 8 consecutive t as fp16x8, one 16B write
#pragma unroll
        for (int i = 0; i < 2; ++i) {
            int e = tid + i * 512;
            if (e < 800) {
                int n = e % 200, q = e / 200;            // q: t-octet within chunk
                const float* s0 = &SrawF[(q * 8) * 212 + n];
                uint4 pk;
                pk.x = f2h(s0[0 * 212]) | (f2h(s0[1 * 212]) << 16);
                pk.y = f2h(s0[2 * 212]) | (f2h(s0[3 * 212]) << 16);
                pk.z = f2h(s0[4 * 212]) | (f2h(s0[5 * 212]) << 16);
                pk.w = f2h(s0[6 * 212]) | (f2h(s0[7 * 212]) << 16);
                *(uint4*)(LDS + n * XRS + c * 64 + q * 16) = pk;
            }
        }
        __syncthreads();
    }

    // ---- phase 2: per-node stats (16B row reads, skewed rows -> conflict-free) ----
    if (tid < 200) {
        float s = 0.f, ss = 0.f;
#pragma unroll 4
        for (int blk = 0; blk < 32; ++blk) {
            short8 v = *(const short8*)(LDS + tid * XRS + blk * 16);
#pragma unroll
            for (int e = 0; e < 8; ++e) {
                float f = h2f((unsigned short)v[e]);
                s += f; ss += f * f;
            }
        }
        float mu = s * (1.f / T);
        float var = ss - s * mu;
        muA[tid] = mu;
        rsA[tid] = (var > 0.f) ? rsqrtf(var) : 0.f;
    }
    __syncthreads();

    // ---- phase 3: normalize in place fp16 -> bf16, uint4 granularity ----
#pragma unroll 4
    for (int i = 0; i < 13; ++i) {
        int u = tid + i * 512;                           // 6400 uint4 units
        if (u < 6400) {
            int n = u % 200, q = u / 200;                // q in 0..31
            uint4* p = (uint4*)(LDS + n * XRS + q * 16);
            uint4 v = *p;
            float m = muA[n], r = rsA[n];
            v.x = norm2(v.x, m, r);
            v.y = norm2(v.y, m, r);
            v.z = norm2(v.z, m, r);
            v.w = norm2(v.w, m, r);
            *p = v;
        }
    }
    __syncthreads();

    // ---- phase 4: corr MFMA, 32x32x16, wave = row-panel, 7 col-tiles ----
    f32x16 acc[7] = {};
    if (wid < 7) {
        int arow = wid * 32 + l31; if (arow > 199) arow = 199;
        int bcc[7];
#pragma unroll
        for (int ct = 0; ct < 7; ++ct) {
            int c2 = ct * 32 + l31; if (c2 > 199) c2 = 199;
            bcc[ct] = c2;
        }
#pragma unroll 2
        for (int kc = 0; kc < 16; ++kc) {
            int kb = kc * 32 + hi * 16;
            short8 a = *(const short8*)(LDS + arow * XRS + kb);
#pragma unroll
            for (int ct = 0; ct < 7; ++ct) {
                short8 bb = *(const short8*)(LDS + bcc[ct] * XRS + kb);
                acc[ct] = __builtin_amdgcn_mfma_f32_32x32x16_bf16(a, bb, acc[ct], 0, 0, 0);
            }
        }
    }
    __syncthreads();     // X dead; reuse LDS[0..92800) as A image

    // ---- phase 5: dump |acc| -> A[200][232] bf16 linear + zero pads ----
    unsigned short* A16 = (unsigned short*)LDS;
    if (wid < 7) {
#pragma unroll
        for (int ct = 0; ct < 7; ++ct) {
            int col = ct * 32 + l31;
            if (col < 200) {
#pragma unroll
                for (int r = 0; r < 16; ++r) {
                    int row = wid * 32 + (r & 3) + 8 * (r >> 2) + 4 * hi;
                    if (row < 200)
                        A16[row * ARS + col] = (unsigned short)bf16r(fabsf(acc[ct][r]));
                }
            }
        }
    }
    // pad cols 200..231 = 0 (full 64B range [400,464) per row)
    for (int e = tid; e < 3200; e += 512) {
        int row = e >> 4, pc = e & 15;
        *(unsigned*)(LDS + row * 464 + 400 + pc * 4) = 0;
    }
    __syncthreads();

    // ---- phase 6: row sums -> dinv; coalesced A copy-out ----
    if (tid < 200) {
        float s = 1.f;                                   // the +I
#pragma unroll 4
        for (int e2 = 0; e2 < 29; ++e2) {
            short8 v = *(const short8*)(LDS + tid * 464 + e2 * 16);
#pragma unroll
            for (int j = 0; j < 8; ++j) s += bf2f((unsigned short)v[j]);
        }
        dinv[b * N + tid] = rsqrtf(s);
    }
    {
        const uint4* s4 = (const uint4*)LDS;
        uint4* g4 = (uint4*)(Abf + (size_t)b * ASAMP);
        for (int u = tid; u < 5800; u += 512) g4[u] = s4[u];
    }
}

// ================= K2: fused full GCN =================
#define OFF_A    0
#define OFF_YT   92800
#define OFF_BUF2 122496
#define OFF_W2T  152192
#define OFF_DINV 161408
#define OFF_B1   162208
#define OFF_B2   162464
#define LDS_SZ   162720

__device__ __forceinline__ void gemm4(const unsigned char* LDSp, int aA,
                                      int bA0, int bA1, int bA2, int bA3,
                                      int nCh, f32x4* acc) {
    for (int s = 0; s < nCh; ++s) {
        int ko = s * 64;
        short8 av = *(const short8*)(LDSp + aA + ko);
        acc[0] = __builtin_amdgcn_mfma_f32_16x16x32_bf16(av, *(const short8*)(LDSp + bA0 + ko), acc[0], 0, 0, 0);
        acc[1] = __builtin_amdgcn_mfma_f32_16x16x32_bf16(av, *(const short8*)(LDSp + bA1 + ko), acc[1], 0, 0, 0);
        acc[2] = __builtin_amdgcn_mfma_f32_16x16x32_bf16(av, *(const short8*)(LDSp + bA2 + ko), acc[2], 0, 0, 0);
        acc[3] = __builtin_amdgcn_mfma_f32_16x16x32_bf16(av, *(const short8*)(LDSp + bA3 + ko), acc[3], 0, 0, 0);
    }
}

__global__ __launch_bounds__(512) void k_gcn(const unsigned short* __restrict__ Abf,
                                             const float* __restrict__ W1,
                                             const float* __restrict__ b1,
                                             const float* __restrict__ W2,
                                             const float* __restrict__ b2,
                                             const float* __restrict__ dinv,
                                             float* __restrict__ out) {
    __shared__ __align__(16) unsigned char LDS[LDS_SZ];
    const int tid = threadIdx.x;
    const int b = blockIdx.x;
    const int lane = tid & 63;
    const int l15 = lane & 15;
    const int hi = lane >> 4;
    const int wid = tid >> 6;

    // ---- stage ----
    {
        const uint4* gs = (const uint4*)(Abf + (size_t)b * ASAMP);
        uint4* dv4 = (uint4*)(LDS + OFF_A);
        for (int u = tid; u < 5800; u += 512) dv4[u] = gs[u];
    }
    for (int e = tid; e < N * H; e += 512) {
        int k = e >> 6, l = e & 63;
        *(unsigned short*)(LDS + OFF_BUF2 + l * 464 + k * 2) = (unsigned short)bf16r(W1[e]);
    }
    for (int e = tid; e < 64 * 16; e += 512) {
        int l = e >> 4, d = e & 15;
        *(unsigned*)(LDS + OFF_BUF2 + l * 464 + 400 + d * 4) = 0;
        *(unsigned*)(LDS + OFF_YT + l * 464 + 400 + d * 4) = 0;
    }
    for (int e = tid; e < H * H; e += 512) {
        int k = e >> 6, l = e & 63;
        *(unsigned short*)(LDS + OFF_W2T + l * 144 + k * 2) = (unsigned short)bf16r(W2[e]);
    }
    if (tid < 200) *(float*)(LDS + OFF_DINV + tid * 4) = dinv[b * N + tid];
    if (tid < 64) *(float*)(LDS + OFF_B1 + tid * 4) = b1[tid];
    else if (tid < 128) *(float*)(LDS + OFF_B2 + (tid - 64) * 4) = b2[tid - 64];
    __syncthreads();

    // ---- G1: t1 = A @ W1; y = dinv*t1 -> Yt (bf16 [l][j]) ----
    for (int rt = wid; rt < 13; rt += 8) {
        int row = rt * 16 + l15; int rowc = (row < 200) ? row : 199;
        f32x4 acc[4] = {};
        gemm4(LDS, OFF_A + rowc * 464 + hi * 16,
              OFF_BUF2 + (l15) * 464 + hi * 16,
              OFF_BUF2 + (16 + l15) * 464 + hi * 16,
              OFF_BUF2 + (32 + l15) * 464 + hi * 16,
              OFF_BUF2 + (48 + l15) * 464 + hi * 16, 7, acc);
        int j0 = rt * 16 + hi * 4;
        if (j0 < 200) {
            float d0 = *(const float*)(LDS + OFF_DINV + (j0 + 0) * 4);
            float d1 = *(const float*)(LDS + OFF_DINV + (j0 + 1) * 4);
            float d2 = *(const float*)(LDS + OFF_DINV + (j0 + 2) * 4);
            float d3 = *(const float*)(LDS + OFF_DINV + (j0 + 3) * 4);
#pragma unroll
            for (int ct = 0; ct < 4; ++ct) {
                int c = ct * 16 + l15;
                unsigned u0 = bf16r(d0 * acc[ct][0]) | (bf16r(d1 * acc[ct][1]) << 16);
                unsigned u1 = bf16r(d2 * acc[ct][2]) | (bf16r(d3 * acc[ct][3]) << 16);
                uint2 uu; uu.x = u0; uu.y = u1;
                *(uint2*)(LDS + OFF_YT + c * 464 + j0 * 2) = uu;
            }
        }
    }
    __syncthreads();

    // ---- G2: z = A @ y; h = relu(dinv_i*(z + y_i) + b1) -> BUF2 ----
    for (int rt = wid; rt < 13; rt += 8) {
        int row = rt * 16 + l15; int rowc = (row < 200) ? row : 199;
        f32x4 acc[4] = {};
        gemm4(LDS, OFF_A + rowc * 464 + hi * 16,
              OFF_YT + (l15) * 464 + hi * 16,
              OFF_YT + (16 + l15) * 464 + hi * 16,
              OFF_YT + (32 + l15) * 464 + hi * 16,
              OFF_YT + (48 + l15) * 464 + hi * 16, 7, acc);
#pragma unroll
        for (int ct = 0; ct < 4; ++ct) {
            int c = ct * 16 + l15;
            float bias = *(const float*)(LDS + OFF_B1 + c * 4);
#pragma unroll
            for (int r = 0; r < 4; ++r) {
                int i = rt * 16 + hi * 4 + r;
                if (i < 200) {
                    float dv = *(const float*)(LDS + OFF_DINV + i * 4);
                    float yi = bf2f(*(const unsigned short*)(LDS + OFF_YT + c * 464 + i * 2));
                    float v = dv * (acc[ct][r] + yi) + bias;
                    *(unsigned short*)(LDS + OFF_BUF2 + i * 144 + c * 2) =
                        (unsigned short)bf16r(fmaxf(v, 0.f));
                }
            }
        }
    }
    __syncthreads();

    // ---- G3: t2 = h @ W2; y2 = dinv*t2 -> Yt ----
    for (int rt = wid; rt < 13; rt += 8) {
        int row = rt * 16 + l15; int rowc = (row < 200) ? row : 199;
        f32x4 acc[4] = {};
        gemm4(LDS, OFF_BUF2 + rowc * 144 + hi * 16,
              OFF_W2T + (l15) * 144 + hi * 16,
              OFF_W2T + (16 + l15) * 144 + hi * 16,
              OFF_W2T + (32 + l15) * 144 + hi * 16,
              OFF_W2T + (48 + l15) * 144 + hi * 16, 2, acc);
        int j0 = rt * 16 + hi * 4;
        if (j0 < 200) {
            float d0 = *(const float*)(LDS + OFF_DINV + (j0 + 0) * 4);
            float d1 = *(const float*)(LDS + OFF_DINV + (j0 + 1) * 4);
            float d2 = *(const float*)(LDS + OFF_DINV + (j0 + 2) * 4);
            float d3 = *(const float*)(LDS + OFF_DINV + (j0 + 3) * 4);
#pragma unroll
            for (int ct = 0; ct < 4; ++ct) {
                int c = ct * 16 + l15;
                unsigned u0 = bf16r(d0 * acc[ct][0]) | (bf16r(d1 * acc[ct][1]) << 16);
                unsigned u1 = bf16r(d2 * acc[ct][2]) | (bf16r(d3 * acc[ct][3]) << 16);
                uint2 uu; uu.x = u0; uu.y = u1;
                *(uint2*)(LDS + OFF_YT + c * 464 + j0 * 2) = uu;
            }
        }
    }
    __syncthreads();

    // ---- G4: z2 = A @ y2; out = relu(dinv_i*(z2 + y2_i) + b2) ----
    for (int rt = wid; rt < 13; rt += 8) {
        int row = rt * 16 + l15; int rowc = (row < 200) ? row : 199;
        f32x4 acc[4] = {};
        gemm4(LDS, OFF_A + rowc * 464 + hi * 16,
              OFF_YT + (l15) * 464 + hi * 16,
              OFF_YT + (16 + l15) * 464 + hi * 16,
              OFF_YT + (32 + l15) * 464 + hi * 16,
              OFF_YT + (48 + l15) * 464 + hi * 16, 7, acc);
#pragma unroll
        for (int ct = 0; ct < 4; ++ct) {
            int c = ct * 16 + l15;
            float bias = *(const float*)(LDS + OFF_B2 + c * 4);
#pragma unroll
            for (int r = 0; r < 4; ++r) {
                int i = rt * 16 + hi * 4 + r;
                if (i < 200) {
                    float dv = *(const float*)(LDS + OFF_DINV + i * 4);
                    float yi = bf2f(*(const unsigned short*)(LDS + OFF_YT + c * 464 + i * 2));
                    float v = dv * (acc[ct][r] + yi) + bias;
                    out[((size_t)b * N + i) * H + c] = fmaxf(v, 0.f);
                }
            }
        }
    }
}

extern "C" void kernel_launch(void* const* d_in, const int* in_sizes, int n_in,
                              void* d_out, int out_size, void* d_ws, size_t ws_size,
                              hipStream_t stream) {
    const float* data = (const float*)d_in[0];
    const float* W1   = (const float*)d_in[1];
    const float* b1   = (const float*)d_in[2];
    const float* W2   = (const float*)d_in[3];
    const float* b2   = (const float*)d_in[4];
    float* out = (float*)d_out;

    unsigned short* Abf = (unsigned short*)d_ws;          // 512*46400 bf16 = 47.5 MB
    float* dinv = (float*)(Abf + (size_t)B * ASAMP);      // 102400 f32 -> total ~47.9 MB

    hipLaunchKernelGGL(k_corr, dim3(B), dim3(512), 0, stream, data, Abf, dinv);
    hipLaunchKernelGGL(k_gcn,  dim3(B), dim3(512), 0, stream, Abf, W1, b1, W2, b2, dinv, out);
}